// Round 3
// baseline (12919.226 us; speedup 1.0000x reference)
//
#include <hip/hip_runtime.h>

#define N_NODES 1024
#define E_EDGES 524288
#define FE 64
#define FC 128
#define NLAYERS 3

typedef unsigned short u16;

__device__ __forceinline__ float bf2f(u16 u) {
    return __uint_as_float(((unsigned)u) << 16);
}
__device__ __forceinline__ u16 f2bf(float f) {
    unsigned x = __float_as_uint(f);
    return (u16)((x + 0x7FFFu + ((x >> 16) & 1u)) >> 16);   // RNE
}

// ---------------------------------------------------------------------------
// Node projections: fni = node@W_ni (bf16), fnj = node@W_nj (bf16),
// h = node@W_node + bias (fp32). Also resets z[d] = 0.
// ---------------------------------------------------------------------------
__global__ __launch_bounds__(256) void node_kernel(
    const float* __restrict__ node,
    const float* __restrict__ Wni, const float* __restrict__ Wnj,
    const float* __restrict__ Wnode, const float* __restrict__ bias,
    u16* __restrict__ fni, u16* __restrict__ fnj,
    float* __restrict__ h, float* __restrict__ z)
{
    __shared__ float row[FC];
    const int d = blockIdx.x;
    if (threadIdx.x < FC) row[threadIdx.x] = node[d * FC + threadIdx.x];
    if (threadIdx.x == 0) z[d] = 0.f;
    __syncthreads();

    const int t = threadIdx.x;
    if (t < 64) {
        float a = 0.f;
        #pragma unroll 8
        for (int k = 0; k < FC; k++) a = fmaf(row[k], Wni[k * FE + t], a);
        fni[d * FE + t] = f2bf(a);
    } else if (t < 128) {
        const int f = t - 64;
        float a = 0.f;
        #pragma unroll 8
        for (int k = 0; k < FC; k++) a = fmaf(row[k], Wnj[k * FE + f], a);
        fnj[d * FE + f] = f2bf(a);
    } else {
        const int c = t - 128;
        float a = bias[c];
        #pragma unroll 8
        for (int k = 0; k < FC; k++) a = fmaf(row[k], Wnode[k * FC + c], a);
        h[d * FC + c] = a;
    }
}

// ---------------------------------------------------------------------------
// Fused edge kernel. For each edge e:
//   f_out = leaky_relu(fni[src] + fnj[dst] + ef@W_fij, 0.2)
//   ef'   = ef + f_out   (bf16, in place; skipped on last layer)
//   p[e]  = exp(f_out . attn)   (no max-shift: logits bounded, fp32-safe)
//   z[dst] += p[e]
// Wave = 16 consecutive edges; step t: groups g=0..3 handle edges base+4t+g,
// so every ef access is one contiguous 512 B wave block.
// __launch_bounds__(256,4): VGPR cap 128 (16 waves/CU). (256,3) capped at 84
// and spilled catastrophically (round 2: 13 GB scratch traffic/dispatch).
// ---------------------------------------------------------------------------
template <bool FIRST, bool WRITE_EF>
__global__ __launch_bounds__(256, 4) void edge_kernel(
    u16* __restrict__ ef,                 // [E][64] bf16 (in/out)
    const float* __restrict__ x,          // edge_feature [E][2]  (FIRST only)
    const float* __restrict__ Win,        // [2][64]              (FIRST only)
    const float* __restrict__ bin,        // [64]                 (FIRST only)
    const u16* __restrict__ fni, const u16* __restrict__ fnj,
    const int* __restrict__ src, const int* __restrict__ dst,
    const float* __restrict__ Wfij,       // [64][64]
    const float* __restrict__ attn,       // [64]
    float* __restrict__ p, float* __restrict__ z)
{
    __shared__ float Wl[FE * FE];
    __shared__ float al[FE];
    __shared__ float w0l[FE], w1l[FE], bl[FE];
    for (int i = threadIdx.x; i < FE * FE; i += 256) Wl[i] = Wfij[i];
    if (threadIdx.x < FE) {
        al[threadIdx.x] = attn[threadIdx.x];
        if (FIRST) {
            w0l[threadIdx.x] = Win[threadIdx.x];
            w1l[threadIdx.x] = Win[FE + threadIdx.x];
            bl[threadIdx.x]  = bin[threadIdx.x];
        }
    }
    __syncthreads();

    const int lane = threadIdx.x & 63;
    const int waveId = threadIdx.x >> 6;
    const int g = lane >> 4;          // group (edge slot) within wave
    const int l16 = lane & 15;        // 16 lanes per edge, 4 feats each

    for (int base = blockIdx.x * 64; base < E_EDGES; base += gridDim.x * 64) {
        const int wbase = base + waveId * 16;

        float4 efv[4], acc[4];
        int d4[4];
        #pragma unroll
        for (int t = 0; t < 4; t++) {
            const int e = wbase + 4 * t + g;
            if (FIRST) {
                const float2 xx = *reinterpret_cast<const float2*>(x + 2 * (size_t)e);
                efv[t].x = fmaf(xx.x, w0l[l16*4+0], fmaf(xx.y, w1l[l16*4+0], bl[l16*4+0]));
                efv[t].y = fmaf(xx.x, w0l[l16*4+1], fmaf(xx.y, w1l[l16*4+1], bl[l16*4+1]));
                efv[t].z = fmaf(xx.x, w0l[l16*4+2], fmaf(xx.y, w1l[l16*4+2], bl[l16*4+2]));
                efv[t].w = fmaf(xx.x, w0l[l16*4+3], fmaf(xx.y, w1l[l16*4+3], bl[l16*4+3]));
            } else {
                const ushort4 u = *reinterpret_cast<const ushort4*>(ef + (size_t)e * FE + l16 * 4);
                efv[t] = make_float4(bf2f(u.x), bf2f(u.y), bf2f(u.z), bf2f(u.w));
            }
            const int s = src[e];
            d4[t] = dst[e];
            const ushort4 a = *reinterpret_cast<const ushort4*>(fni + (size_t)s * FE + l16 * 4);
            const ushort4 b = *reinterpret_cast<const ushort4*>(fnj + (size_t)d4[t] * FE + l16 * 4);
            acc[t] = make_float4(bf2f(a.x) + bf2f(b.x), bf2f(a.y) + bf2f(b.y),
                                 bf2f(a.z) + bf2f(b.z), bf2f(a.w) + bf2f(b.w));
        }

        // acc[t][f] += sum_k efv[t][k] * W[k][f],  f = l16*4 .. l16*4+3
        // w loads split in halves to shorten live ranges (spill headroom).
        #pragma unroll
        for (int k4 = 0; k4 < 16; k4++) {
            {
                const float4 w0 = *reinterpret_cast<const float4*>(&Wl[(k4*4+0)*FE + l16*4]);
                const float4 w1 = *reinterpret_cast<const float4*>(&Wl[(k4*4+1)*FE + l16*4]);
                #pragma unroll
                for (int t = 0; t < 4; t++) {
                    const float e0 = __shfl(efv[t].x, k4, 16);
                    const float e1 = __shfl(efv[t].y, k4, 16);
                    acc[t].x = fmaf(e0, w0.x, acc[t].x); acc[t].y = fmaf(e0, w0.y, acc[t].y);
                    acc[t].z = fmaf(e0, w0.z, acc[t].z); acc[t].w = fmaf(e0, w0.w, acc[t].w);
                    acc[t].x = fmaf(e1, w1.x, acc[t].x); acc[t].y = fmaf(e1, w1.y, acc[t].y);
                    acc[t].z = fmaf(e1, w1.z, acc[t].z); acc[t].w = fmaf(e1, w1.w, acc[t].w);
                }
            }
            {
                const float4 w2 = *reinterpret_cast<const float4*>(&Wl[(k4*4+2)*FE + l16*4]);
                const float4 w3 = *reinterpret_cast<const float4*>(&Wl[(k4*4+3)*FE + l16*4]);
                #pragma unroll
                for (int t = 0; t < 4; t++) {
                    const float e2 = __shfl(efv[t].z, k4, 16);
                    const float e3 = __shfl(efv[t].w, k4, 16);
                    acc[t].x = fmaf(e2, w2.x, acc[t].x); acc[t].y = fmaf(e2, w2.y, acc[t].y);
                    acc[t].z = fmaf(e2, w2.z, acc[t].z); acc[t].w = fmaf(e2, w2.w, acc[t].w);
                    acc[t].x = fmaf(e3, w3.x, acc[t].x); acc[t].y = fmaf(e3, w3.y, acc[t].y);
                    acc[t].z = fmaf(e3, w3.z, acc[t].z); acc[t].w = fmaf(e3, w3.w, acc[t].w);
                }
            }
        }

        const float4 av = *reinterpret_cast<const float4*>(&al[l16 * 4]);
        #pragma unroll
        for (int t = 0; t < 4; t++) {
            const int e = wbase + 4 * t + g;
            float4 f;
            f.x = acc[t].x > 0.f ? acc[t].x : 0.2f * acc[t].x;
            f.y = acc[t].y > 0.f ? acc[t].y : 0.2f * acc[t].y;
            f.z = acc[t].z > 0.f ? acc[t].z : 0.2f * acc[t].z;
            f.w = acc[t].w > 0.f ? acc[t].w : 0.2f * acc[t].w;
            if (WRITE_EF) {
                ushort4 st;
                st.x = f2bf(efv[t].x + f.x);
                st.y = f2bf(efv[t].y + f.y);
                st.z = f2bf(efv[t].z + f.z);
                st.w = f2bf(efv[t].w + f.w);
                *reinterpret_cast<ushort4*>(ef + (size_t)e * FE + l16 * 4) = st;
            }
            float part = f.x * av.x + f.y * av.y + f.z * av.z + f.w * av.w;
            part += __shfl_xor(part, 1, 16);
            part += __shfl_xor(part, 2, 16);
            part += __shfl_xor(part, 4, 16);
            part += __shfl_xor(part, 8, 16);
            if (l16 == 0) {
                const float pv = expf(part);
                p[e] = pv;
                atomicAdd(z + d4[t], pv);
            }
        }
    }
}

// ---------------------------------------------------------------------------
// a[e] = p[e] / z[dst[e]]; scatter into dense S[dst][src] += a
// ---------------------------------------------------------------------------
__global__ __launch_bounds__(256) void scatter_kernel(
    const float* __restrict__ p, const float* __restrict__ z,
    const int* __restrict__ src, const int* __restrict__ dst,
    float* __restrict__ S)
{
    const int e = blockIdx.x * 256 + threadIdx.x;
    if (e < E_EDGES) {
        const int d = dst[e];
        const float a = p[e] / z[d];
        atomicAdd(S + (size_t)d * N_NODES + src[e], a);
    }
}

// ---------------------------------------------------------------------------
// node_out = node_in + S @ h.
// ---------------------------------------------------------------------------
__global__ __launch_bounds__(256) void spmm_kernel(
    const float* __restrict__ S, const float* __restrict__ h,
    const float* __restrict__ nin, float* __restrict__ nout)
{
    __shared__ float red[256];
    const int d = blockIdx.x;
    const int c = threadIdx.x & 127;
    const int half = threadIdx.x >> 7;
    const float* Srow = S + (size_t)d * N_NODES + half * 512;
    const float* hp = h + (size_t)half * 512 * FC;
    float acc = 0.f;
    #pragma unroll 8
    for (int n = 0; n < 512; n++) {
        acc = fmaf(Srow[n], hp[n * FC + c], acc);
    }
    red[threadIdx.x] = acc;
    __syncthreads();
    if (half == 0) {
        nout[d * FC + c] = nin[d * FC + c] + red[c] + red[128 + c];
    }
}

// ---------------------------------------------------------------------------
extern "C" void kernel_launch(void* const* d_in, const int* in_sizes, int n_in,
                              void* d_out, int out_size, void* d_ws, size_t ws_size,
                              hipStream_t stream)
{
    const float* node_feature = (const float*)d_in[0];
    const float* edge_feature = (const float*)d_in[1];
    const int*   src          = (const int*)d_in[2];
    const int*   dst          = (const int*)d_in[3];
    const float* W_in         = (const float*)d_in[4];
    const float* b_in         = (const float*)d_in[5];
    const float* W_ni         = (const float*)d_in[6];
    const float* W_nj         = (const float*)d_in[7];
    const float* W_fij        = (const float*)d_in[8];
    const float* W_node       = (const float*)d_in[9];
    const float* attn         = (const float*)d_in[10];
    const float* bias_node    = (const float*)d_in[11];
    float* out = (float*)d_out;

    char* ws = (char*)d_ws;
    size_t off = 0;
    auto alloc = [&](size_t bytes) -> void* {
        void* pp = ws + off;
        off += (bytes + 255) & ~(size_t)255;
        return pp;
    };
    u16*   ef    = (u16*)alloc((size_t)E_EDGES * FE * sizeof(u16));       // 67 MB
    float* p     = (float*)alloc((size_t)E_EDGES * sizeof(float));
    float* z     = (float*)alloc(N_NODES * sizeof(float));
    u16*   fni   = (u16*)alloc(N_NODES * FE * sizeof(u16));
    u16*   fnj   = (u16*)alloc(N_NODES * FE * sizeof(u16));
    float* h     = (float*)alloc(N_NODES * FC * sizeof(float));
    float* S     = (float*)alloc((size_t)N_NODES * N_NODES * sizeof(float)); // 4 MB
    float* nodeA = (float*)alloc(N_NODES * FC * sizeof(float));

    hipMemcpyAsync(nodeA, node_feature, N_NODES * FC * sizeof(float),
                   hipMemcpyDeviceToDevice, stream);

    for (int l = 0; l < NLAYERS; l++) {
        const float* node_in = nodeA;
        float* node_out = (l == NLAYERS - 1) ? out : nodeA;

        node_kernel<<<N_NODES, 256, 0, stream>>>(
            node_in, W_ni + (size_t)l * FC * FE, W_nj + (size_t)l * FC * FE,
            W_node + (size_t)l * FC * FC, bias_node + (size_t)l * FC,
            fni, fnj, h, z);

        hipMemsetAsync(S, 0, (size_t)N_NODES * N_NODES * sizeof(float), stream);

        if (l == 0) {
            edge_kernel<true, true><<<2048, 256, 0, stream>>>(
                ef, edge_feature, W_in, b_in, fni, fnj, src, dst,
                W_fij + (size_t)l * FE * FE, attn + (size_t)l * FE, p, z);
        } else if (l == NLAYERS - 1) {
            edge_kernel<false, false><<<2048, 256, 0, stream>>>(
                ef, nullptr, nullptr, nullptr, fni, fnj, src, dst,
                W_fij + (size_t)l * FE * FE, attn + (size_t)l * FE, p, z);
        } else {
            edge_kernel<false, true><<<2048, 256, 0, stream>>>(
                ef, nullptr, nullptr, nullptr, fni, fnj, src, dst,
                W_fij + (size_t)l * FE * FE, attn + (size_t)l * FE, p, z);
        }

        scatter_kernel<<<E_EDGES / 256, 256, 0, stream>>>(p, z, src, dst, S);

        spmm_kernel<<<N_NODES, 256, 0, stream>>>(S, h, node_in, node_out);
    }
}

// Round 4
// 11643.922 us; speedup vs baseline: 1.1095x; 1.1095x over previous
//
#include <hip/hip_runtime.h>

#define N_NODES 1024
#define E_EDGES 524288
#define FE 64
#define FC 128
#define NLAYERS 3

typedef unsigned short u16;

__device__ __forceinline__ float bf2f(u16 u) {
    return __uint_as_float(((unsigned)u) << 16);
}
__device__ __forceinline__ u16 f2bf(float f) {
    unsigned x = __float_as_uint(f);
    return (u16)((x + 0x7FFFu + ((x >> 16) & 1u)) >> 16);   // RNE
}

// ---------------------------------------------------------------------------
// Node projections: fni = node@W_ni (bf16), fnj = node@W_nj (bf16),
// h = node@W_node + bias (fp32). Also resets z[d] = 0.
// ---------------------------------------------------------------------------
__global__ __launch_bounds__(256) void node_kernel(
    const float* __restrict__ node,
    const float* __restrict__ Wni, const float* __restrict__ Wnj,
    const float* __restrict__ Wnode, const float* __restrict__ bias,
    u16* __restrict__ fni, u16* __restrict__ fnj,
    float* __restrict__ h, float* __restrict__ z)
{
    __shared__ float row[FC];
    const int d = blockIdx.x;
    if (threadIdx.x < FC) row[threadIdx.x] = node[d * FC + threadIdx.x];
    if (threadIdx.x == 0) z[d] = 0.f;
    __syncthreads();

    const int t = threadIdx.x;
    if (t < 64) {
        float a = 0.f;
        #pragma unroll 8
        for (int k = 0; k < FC; k++) a = fmaf(row[k], Wni[k * FE + t], a);
        fni[d * FE + t] = f2bf(a);
    } else if (t < 128) {
        const int f = t - 64;
        float a = 0.f;
        #pragma unroll 8
        for (int k = 0; k < FC; k++) a = fmaf(row[k], Wnj[k * FE + f], a);
        fnj[d * FE + f] = f2bf(a);
    } else {
        const int c = t - 128;
        float a = bias[c];
        #pragma unroll 8
        for (int k = 0; k < FC; k++) a = fmaf(row[k], Wnode[k * FC + c], a);
        h[d * FC + c] = a;
    }
}

// ---------------------------------------------------------------------------
// Fused edge kernel — ONE 64-edge tile per block (grid = E/64), no loop.
// NOTE (r2/r3 lesson): __launch_bounds__ caps and grid-stride loops both
// triggered catastrophic scratch spilling (10+ GB TCC traffic). Keep this
// kernel straight-line with no occupancy cap.
// For each edge e:
//   f_out = leaky_relu(fni[src] + fnj[dst] + ef@W_fij, 0.2)
//   ef'   = ef + f_out   (bf16, in place; skipped on last layer)
//   p[e]  = exp(f_out . attn)
//   z[dst] += p[e]
// Wave = 16 consecutive edges; step t: groups g=0..3 handle edges
// wbase+4t+g, so every ef access is one contiguous 512 B wave block.
// ---------------------------------------------------------------------------
template <bool FIRST, bool WRITE_EF>
__global__ void edge_kernel(
    u16* __restrict__ ef,                 // [E][64] bf16 (in/out)
    const float* __restrict__ x,          // edge_feature [E][2]  (FIRST only)
    const float* __restrict__ Win,        // [2][64]              (FIRST only)
    const float* __restrict__ bin,        // [64]                 (FIRST only)
    const u16* __restrict__ fni, const u16* __restrict__ fnj,
    const int* __restrict__ src, const int* __restrict__ dst,
    const float* __restrict__ Wfij,       // [64][64]
    const float* __restrict__ attn,       // [64]
    float* __restrict__ p, float* __restrict__ z)
{
    __shared__ float Wl[FE * FE];
    __shared__ float al[FE];
    __shared__ float w0l[FE], w1l[FE], bl[FE];
    for (int i = threadIdx.x; i < FE * FE; i += 256) Wl[i] = Wfij[i];
    if (threadIdx.x < FE) {
        al[threadIdx.x] = attn[threadIdx.x];
        if (FIRST) {
            w0l[threadIdx.x] = Win[threadIdx.x];
            w1l[threadIdx.x] = Win[FE + threadIdx.x];
            bl[threadIdx.x]  = bin[threadIdx.x];
        }
    }
    __syncthreads();

    const int lane = threadIdx.x & 63;
    const int waveId = threadIdx.x >> 6;
    const int g = lane >> 4;          // group (edge slot) within wave
    const int l16 = lane & 15;        // 16 lanes per edge, 4 feats each

    const int wbase = blockIdx.x * 64 + waveId * 16;

    float4 efv[4], acc[4];
    int d4[4];
    #pragma unroll
    for (int t = 0; t < 4; t++) {
        const int e = wbase + 4 * t + g;
        if (FIRST) {
            const float2 xx = *reinterpret_cast<const float2*>(x + 2 * (size_t)e);
            efv[t].x = fmaf(xx.x, w0l[l16*4+0], fmaf(xx.y, w1l[l16*4+0], bl[l16*4+0]));
            efv[t].y = fmaf(xx.x, w0l[l16*4+1], fmaf(xx.y, w1l[l16*4+1], bl[l16*4+1]));
            efv[t].z = fmaf(xx.x, w0l[l16*4+2], fmaf(xx.y, w1l[l16*4+2], bl[l16*4+2]));
            efv[t].w = fmaf(xx.x, w0l[l16*4+3], fmaf(xx.y, w1l[l16*4+3], bl[l16*4+3]));
        } else {
            const ushort4 u = *reinterpret_cast<const ushort4*>(ef + (size_t)e * FE + l16 * 4);
            efv[t] = make_float4(bf2f(u.x), bf2f(u.y), bf2f(u.z), bf2f(u.w));
        }
        const int s = src[e];
        d4[t] = dst[e];
        const ushort4 a = *reinterpret_cast<const ushort4*>(fni + (size_t)s * FE + l16 * 4);
        const ushort4 b = *reinterpret_cast<const ushort4*>(fnj + (size_t)d4[t] * FE + l16 * 4);
        acc[t] = make_float4(bf2f(a.x) + bf2f(b.x), bf2f(a.y) + bf2f(b.y),
                             bf2f(a.z) + bf2f(b.z), bf2f(a.w) + bf2f(b.w));
    }

    // acc[t][f] += sum_k efv[t][k] * W[k][f],  f = l16*4 .. l16*4+3
    #pragma unroll
    for (int k4 = 0; k4 < 16; k4++) {
        {
            const float4 w0 = *reinterpret_cast<const float4*>(&Wl[(k4*4+0)*FE + l16*4]);
            const float4 w1 = *reinterpret_cast<const float4*>(&Wl[(k4*4+1)*FE + l16*4]);
            #pragma unroll
            for (int t = 0; t < 4; t++) {
                const float e0 = __shfl(efv[t].x, k4, 16);
                const float e1 = __shfl(efv[t].y, k4, 16);
                acc[t].x = fmaf(e0, w0.x, acc[t].x); acc[t].y = fmaf(e0, w0.y, acc[t].y);
                acc[t].z = fmaf(e0, w0.z, acc[t].z); acc[t].w = fmaf(e0, w0.w, acc[t].w);
                acc[t].x = fmaf(e1, w1.x, acc[t].x); acc[t].y = fmaf(e1, w1.y, acc[t].y);
                acc[t].z = fmaf(e1, w1.z, acc[t].z); acc[t].w = fmaf(e1, w1.w, acc[t].w);
            }
        }
        {
            const float4 w2 = *reinterpret_cast<const float4*>(&Wl[(k4*4+2)*FE + l16*4]);
            const float4 w3 = *reinterpret_cast<const float4*>(&Wl[(k4*4+3)*FE + l16*4]);
            #pragma unroll
            for (int t = 0; t < 4; t++) {
                const float e2 = __shfl(efv[t].z, k4, 16);
                const float e3 = __shfl(efv[t].w, k4, 16);
                acc[t].x = fmaf(e2, w2.x, acc[t].x); acc[t].y = fmaf(e2, w2.y, acc[t].y);
                acc[t].z = fmaf(e2, w2.z, acc[t].z); acc[t].w = fmaf(e2, w2.w, acc[t].w);
                acc[t].x = fmaf(e3, w3.x, acc[t].x); acc[t].y = fmaf(e3, w3.y, acc[t].y);
                acc[t].z = fmaf(e3, w3.z, acc[t].z); acc[t].w = fmaf(e3, w3.w, acc[t].w);
            }
        }
    }

    const float4 av = *reinterpret_cast<const float4*>(&al[l16 * 4]);
    #pragma unroll
    for (int t = 0; t < 4; t++) {
        const int e = wbase + 4 * t + g;
        float4 f;
        f.x = acc[t].x > 0.f ? acc[t].x : 0.2f * acc[t].x;
        f.y = acc[t].y > 0.f ? acc[t].y : 0.2f * acc[t].y;
        f.z = acc[t].z > 0.f ? acc[t].z : 0.2f * acc[t].z;
        f.w = acc[t].w > 0.f ? acc[t].w : 0.2f * acc[t].w;
        if (WRITE_EF) {
            ushort4 st;
            st.x = f2bf(efv[t].x + f.x);
            st.y = f2bf(efv[t].y + f.y);
            st.z = f2bf(efv[t].z + f.z);
            st.w = f2bf(efv[t].w + f.w);
            *reinterpret_cast<ushort4*>(ef + (size_t)e * FE + l16 * 4) = st;
        }
        float part = f.x * av.x + f.y * av.y + f.z * av.z + f.w * av.w;
        part += __shfl_xor(part, 1, 16);
        part += __shfl_xor(part, 2, 16);
        part += __shfl_xor(part, 4, 16);
        part += __shfl_xor(part, 8, 16);
        if (l16 == 0) {
            const float pv = expf(part);
            p[e] = pv;
            atomicAdd(z + d4[t], pv);
        }
    }
}

// ---------------------------------------------------------------------------
// a[e] = p[e] / z[dst[e]]; scatter into dense S[dst][src] += a
// ---------------------------------------------------------------------------
__global__ __launch_bounds__(256) void scatter_kernel(
    const float* __restrict__ p, const float* __restrict__ z,
    const int* __restrict__ src, const int* __restrict__ dst,
    float* __restrict__ S)
{
    const int e = blockIdx.x * 256 + threadIdx.x;
    if (e < E_EDGES) {
        const int d = dst[e];
        const float a = p[e] / z[d];
        atomicAdd(S + (size_t)d * N_NODES + src[e], a);
    }
}

// ---------------------------------------------------------------------------
// node_out = node_in + S @ h.
// ---------------------------------------------------------------------------
__global__ __launch_bounds__(256) void spmm_kernel(
    const float* __restrict__ S, const float* __restrict__ h,
    const float* __restrict__ nin, float* __restrict__ nout)
{
    __shared__ float red[256];
    const int d = blockIdx.x;
    const int c = threadIdx.x & 127;
    const int half = threadIdx.x >> 7;
    const float* Srow = S + (size_t)d * N_NODES + half * 512;
    const float* hp = h + (size_t)half * 512 * FC;
    float acc = 0.f;
    #pragma unroll 8
    for (int n = 0; n < 512; n++) {
        acc = fmaf(Srow[n], hp[n * FC + c], acc);
    }
    red[threadIdx.x] = acc;
    __syncthreads();
    if (half == 0) {
        nout[d * FC + c] = nin[d * FC + c] + red[c] + red[128 + c];
    }
}

// ---------------------------------------------------------------------------
extern "C" void kernel_launch(void* const* d_in, const int* in_sizes, int n_in,
                              void* d_out, int out_size, void* d_ws, size_t ws_size,
                              hipStream_t stream)
{
    const float* node_feature = (const float*)d_in[0];
    const float* edge_feature = (const float*)d_in[1];
    const int*   src          = (const int*)d_in[2];
    const int*   dst          = (const int*)d_in[3];
    const float* W_in         = (const float*)d_in[4];
    const float* b_in         = (const float*)d_in[5];
    const float* W_ni         = (const float*)d_in[6];
    const float* W_nj         = (const float*)d_in[7];
    const float* W_fij        = (const float*)d_in[8];
    const float* W_node       = (const float*)d_in[9];
    const float* attn         = (const float*)d_in[10];
    const float* bias_node    = (const float*)d_in[11];
    float* out = (float*)d_out;

    char* ws = (char*)d_ws;
    size_t off = 0;
    auto alloc = [&](size_t bytes) -> void* {
        void* pp = ws + off;
        off += (bytes + 255) & ~(size_t)255;
        return pp;
    };
    u16*   ef    = (u16*)alloc((size_t)E_EDGES * FE * sizeof(u16));       // 67 MB
    float* p     = (float*)alloc((size_t)E_EDGES * sizeof(float));
    float* z     = (float*)alloc(N_NODES * sizeof(float));
    u16*   fni   = (u16*)alloc(N_NODES * FE * sizeof(u16));
    u16*   fnj   = (u16*)alloc(N_NODES * FE * sizeof(u16));
    float* h     = (float*)alloc(N_NODES * FC * sizeof(float));
    float* S     = (float*)alloc((size_t)N_NODES * N_NODES * sizeof(float)); // 4 MB
    float* nodeA = (float*)alloc(N_NODES * FC * sizeof(float));

    hipMemcpyAsync(nodeA, node_feature, N_NODES * FC * sizeof(float),
                   hipMemcpyDeviceToDevice, stream);

    for (int l = 0; l < NLAYERS; l++) {
        const float* node_in = nodeA;
        float* node_out = (l == NLAYERS - 1) ? out : nodeA;

        node_kernel<<<N_NODES, 256, 0, stream>>>(
            node_in, W_ni + (size_t)l * FC * FE, W_nj + (size_t)l * FC * FE,
            W_node + (size_t)l * FC * FC, bias_node + (size_t)l * FC,
            fni, fnj, h, z);

        hipMemsetAsync(S, 0, (size_t)N_NODES * N_NODES * sizeof(float), stream);

        if (l == 0) {
            edge_kernel<true, true><<<E_EDGES / 64, 256, 0, stream>>>(
                ef, edge_feature, W_in, b_in, fni, fnj, src, dst,
                W_fij + (size_t)l * FE * FE, attn + (size_t)l * FE, p, z);
        } else if (l == NLAYERS - 1) {
            edge_kernel<false, false><<<E_EDGES / 64, 256, 0, stream>>>(
                ef, nullptr, nullptr, nullptr, fni, fnj, src, dst,
                W_fij + (size_t)l * FE * FE, attn + (size_t)l * FE, p, z);
        } else {
            edge_kernel<false, true><<<E_EDGES / 64, 256, 0, stream>>>(
                ef, nullptr, nullptr, nullptr, fni, fnj, src, dst,
                W_fij + (size_t)l * FE * FE, attn + (size_t)l * FE, p, z);
        }

        scatter_kernel<<<E_EDGES / 256, 256, 0, stream>>>(p, z, src, dst, S);

        spmm_kernel<<<N_NODES, 256, 0, stream>>>(S, h, node_in, node_out);
    }
}

// Round 5
// 856.625 us; speedup vs baseline: 15.0815x; 13.5928x over previous
//
#include <hip/hip_runtime.h>

#define N_NODES 1024
#define E_EDGES 524288
#define FE 64
#define FC 128
#define NLAYERS 3

typedef unsigned short u16;
typedef __attribute__((ext_vector_type(8))) short bf16x8;   // MFMA A/B frag
typedef __attribute__((ext_vector_type(4))) float f32x4;    // MFMA C/D frag
typedef __attribute__((ext_vector_type(8))) unsigned short u16x8;

__device__ __forceinline__ float bf2f(u16 u) {
    return __uint_as_float(((unsigned)u) << 16);
}
__device__ __forceinline__ u16 f2bf(float f) {
    unsigned x = __float_as_uint(f);
    return (u16)((x + 0x7FFFu + ((x >> 16) & 1u)) >> 16);   // RNE
}

// ---------------------------------------------------------------------------
// Wt[l][n][k] = bf16(W_fij[l][k][n])  — transposed bf16 copy so edge kernel
// B-fragments are contiguous 16 B loads.
// ---------------------------------------------------------------------------
__global__ __launch_bounds__(256) void wt_kernel(
    const float* __restrict__ Wfij, u16* __restrict__ Wt)
{
    const int i = blockIdx.x * 256 + threadIdx.x;   // 3*64*64 total
    const int l = i >> 12, rem = i & 4095;
    const int n = rem >> 6, k = rem & 63;
    Wt[(size_t)l * 4096 + n * 64 + k] = f2bf(Wfij[(size_t)l * 4096 + k * 64 + n]);
}

// ---------------------------------------------------------------------------
// ef[e][f] = bf16(x[e,0]*Win[0,f] + x[e,1]*Win[1,f] + b[f])
// 8 threads per edge, 8 feats each; 16 B stores.
// ---------------------------------------------------------------------------
__global__ __launch_bounds__(256) void ef_init_kernel(
    const float* __restrict__ x, const float* __restrict__ Win,
    const float* __restrict__ bin, u16* __restrict__ ef)
{
    const int idx = blockIdx.x * 256 + threadIdx.x;  // E*8 total
    const int e = idx >> 3;
    const int f0 = (idx & 7) * 8;
    const float x0 = x[e * 2], x1 = x[e * 2 + 1];
    u16x8 o;
    #pragma unroll
    for (int j = 0; j < 8; j++) {
        o[j] = f2bf(fmaf(x0, Win[f0 + j], fmaf(x1, Win[FE + f0 + j], bin[f0 + j])));
    }
    *reinterpret_cast<u16x8*>(ef + (size_t)e * FE + f0) = o;
}

// ---------------------------------------------------------------------------
// Node projections: fni = node@W_ni (bf16), fnj = node@W_nj (bf16),
// h = node@W_node + bias (fp32). Also resets z[d] = 0.
// ---------------------------------------------------------------------------
__global__ __launch_bounds__(256) void node_kernel(
    const float* __restrict__ node,
    const float* __restrict__ Wni, const float* __restrict__ Wnj,
    const float* __restrict__ Wnode, const float* __restrict__ bias,
    u16* __restrict__ fni, u16* __restrict__ fnj,
    float* __restrict__ h, float* __restrict__ z)
{
    __shared__ float row[FC];
    const int d = blockIdx.x;
    if (threadIdx.x < FC) row[threadIdx.x] = node[d * FC + threadIdx.x];
    if (threadIdx.x == 0) z[d] = 0.f;
    __syncthreads();

    const int t = threadIdx.x;
    if (t < 64) {
        float a = 0.f;
        #pragma unroll 8
        for (int k = 0; k < FC; k++) a = fmaf(row[k], Wni[k * FE + t], a);
        fni[d * FE + t] = f2bf(a);
    } else if (t < 128) {
        const int f = t - 64;
        float a = 0.f;
        #pragma unroll 8
        for (int k = 0; k < FC; k++) a = fmaf(row[k], Wnj[k * FE + f], a);
        fnj[d * FE + f] = f2bf(a);
    } else {
        const int c = t - 128;
        float a = bias[c];
        #pragma unroll 8
        for (int k = 0; k < FC; k++) a = fmaf(row[k], Wnode[k * FC + c], a);
        h[d * FC + c] = a;
    }
}

// ---------------------------------------------------------------------------
// MFMA edge kernel. Wave = 16 edges, block = 4 waves = 64 edges, one tile
// per block (grid = E/64). No __launch_bounds__, no grid-stride (r2-r4:
// both triggered catastrophic scratch spills on the shuffle-matvec version;
// MFMA version keeps W in 32 VGPRs so the spill driver is gone).
//   F    = EF[16x64] @ W[64x64]            (8x mfma_f32_16x16x32_bf16)
//   f    = leaky_relu(F + fni[src] + fnj[dst], 0.2)
//   ef' += f        (bf16, via per-wave LDS transpose; skipped last layer)
//   p[e] = exp(f . attn);  z[dst] += p[e]
// Fragment layouts (m89-verified family):
//   A: row=lane&15 (edge), k=(lane>>4)*8+j      B: col=lane&15 (n), same k
//   C: col=lane&15 (n),   row=(lane>>4)*4+reg   (edge)
// ---------------------------------------------------------------------------
template <bool WRITE_EF>
__global__ void edge_mfma_kernel(
    u16* __restrict__ ef,                 // [E][64] bf16 (in/out)
    const u16* __restrict__ Wt,           // [64 n][64 k] bf16 (this layer)
    const u16* __restrict__ fni, const u16* __restrict__ fnj,
    const int* __restrict__ src, const int* __restrict__ dst,
    const float* __restrict__ attn,       // [64] fp32
    float* __restrict__ p, float* __restrict__ z)
{
    __shared__ float al[FE];
    __shared__ __align__(16) u16 fo_lds[4][16 * 72];  // row stride 72 u16 = 144 B
    if (threadIdx.x < FE) al[threadIdx.x] = attn[threadIdx.x];
    __syncthreads();

    const int lane = threadIdx.x & 63;
    const int wid  = threadIdx.x >> 6;
    const int l15  = lane & 15;
    const int grp  = lane >> 4;                       // 0..3
    const int wbase = blockIdx.x * 64 + wid * 16;

    // B fragments: Wt[n][k]; n = nt*16+l15, k = ks*32 + grp*8 + j  (16 B each)
    bf16x8 bfr[2][4];
    #pragma unroll
    for (int ks = 0; ks < 2; ks++)
        #pragma unroll
        for (int nt = 0; nt < 4; nt++)
            bfr[ks][nt] = *reinterpret_cast<const bf16x8*>(
                Wt + (size_t)(nt * 16 + l15) * 64 + ks * 32 + grp * 8);

    // A fragments: ef[e][k]; e = wbase+l15, k = ks*32 + grp*8 + j
    const size_t arow = (size_t)(wbase + l15) * FE;
    bf16x8 afr0 = *reinterpret_cast<const bf16x8*>(ef + arow + grp * 8);
    bf16x8 afr1 = *reinterpret_cast<const bf16x8*>(ef + arow + 32 + grp * 8);

    f32x4 acc[4];
    #pragma unroll
    for (int nt = 0; nt < 4; nt++) {
        acc[nt] = (f32x4){0.f, 0.f, 0.f, 0.f};
        acc[nt] = __builtin_amdgcn_mfma_f32_16x16x32_bf16(afr0, bfr[0][nt], acc[nt], 0, 0, 0);
        acc[nt] = __builtin_amdgcn_mfma_f32_16x16x32_bf16(afr1, bfr[1][nt], acc[nt], 0, 0, 0);
    }

    // This lane's 4 edges (C rows): e = wbase + grp*4 + r
    int sidx[4], didx[4];
    #pragma unroll
    for (int r = 0; r < 4; r++) {
        const int e = wbase + grp * 4 + r;
        sidx[r] = src[e];
        didx[r] = dst[e];
    }

    u16* myld = fo_lds[wid];
    float logit[4] = {0.f, 0.f, 0.f, 0.f};
    #pragma unroll
    for (int nt = 0; nt < 4; nt++) {
        const int n = nt * 16 + l15;
        const float an = al[n];
        #pragma unroll
        for (int r = 0; r < 4; r++) {
            float v = acc[nt][r]
                    + bf2f(fni[(size_t)sidx[r] * FE + n])
                    + bf2f(fnj[(size_t)didx[r] * FE + n]);
            v = v > 0.f ? v : 0.2f * v;
            logit[r] = fmaf(v, an, logit[r]);
            if (WRITE_EF) myld[(grp * 4 + r) * 72 + n] = f2bf(v);
        }
    }

    // logit reduce across the 16 lanes sharing each edge
    #pragma unroll
    for (int r = 0; r < 4; r++) {
        float t = logit[r];
        t += __shfl_xor(t, 1, 16);
        t += __shfl_xor(t, 2, 16);
        t += __shfl_xor(t, 4, 16);
        t += __shfl_xor(t, 8, 16);
        if (l15 == 0) {
            const float pv = expf(t);
            p[wbase + grp * 4 + r] = pv;
            atomicAdd(z + didx[r], pv);
        }
    }

    if (WRITE_EF) {
        __syncthreads();   // fo_lds visible (also orders wave-own ds_writes)
        #pragma unroll
        for (int q = 0; q < 2; q++) {
            const int row = (lane >> 3) + q * 8;
            const int f0 = (lane & 7) * 8;
            const u16x8 fo = *reinterpret_cast<const u16x8*>(myld + row * 72 + f0);
            u16* gp = ef + (size_t)(wbase + row) * FE + f0;
            const u16x8 ev = *reinterpret_cast<const u16x8*>(gp);
            u16x8 o;
            #pragma unroll
            for (int j = 0; j < 8; j++) o[j] = f2bf(bf2f(ev[j]) + bf2f(fo[j]));
            *reinterpret_cast<u16x8*>(gp) = o;
        }
    }
}

// ---------------------------------------------------------------------------
// a[e] = p[e] / z[dst[e]]; scatter into dense S[dst][src] += a
// ---------------------------------------------------------------------------
__global__ __launch_bounds__(256) void scatter_kernel(
    const float* __restrict__ p, const float* __restrict__ z,
    const int* __restrict__ src, const int* __restrict__ dst,
    float* __restrict__ S)
{
    const int e = blockIdx.x * 256 + threadIdx.x;
    if (e < E_EDGES) {
        const int d = dst[e];
        const float a = p[e] / z[d];
        atomicAdd(S + (size_t)d * N_NODES + src[e], a);
    }
}

// ---------------------------------------------------------------------------
// node_out = node_in + S @ h.
// ---------------------------------------------------------------------------
__global__ __launch_bounds__(256) void spmm_kernel(
    const float* __restrict__ S, const float* __restrict__ h,
    const float* __restrict__ nin, float* __restrict__ nout)
{
    __shared__ float red[256];
    const int d = blockIdx.x;
    const int c = threadIdx.x & 127;
    const int half = threadIdx.x >> 7;
    const float* Srow = S + (size_t)d * N_NODES + half * 512;
    const float* hp = h + (size_t)half * 512 * FC;
    float acc = 0.f;
    #pragma unroll 8
    for (int n = 0; n < 512; n++) {
        acc = fmaf(Srow[n], hp[n * FC + c], acc);
    }
    red[threadIdx.x] = acc;
    __syncthreads();
    if (half == 0) {
        nout[d * FC + c] = nin[d * FC + c] + red[c] + red[128 + c];
    }
}

// ---------------------------------------------------------------------------
extern "C" void kernel_launch(void* const* d_in, const int* in_sizes, int n_in,
                              void* d_out, int out_size, void* d_ws, size_t ws_size,
                              hipStream_t stream)
{
    const float* node_feature = (const float*)d_in[0];
    const float* edge_feature = (const float*)d_in[1];
    const int*   src          = (const int*)d_in[2];
    const int*   dst          = (const int*)d_in[3];
    const float* W_in         = (const float*)d_in[4];
    const float* b_in         = (const float*)d_in[5];
    const float* W_ni         = (const float*)d_in[6];
    const float* W_nj         = (const float*)d_in[7];
    const float* W_fij        = (const float*)d_in[8];
    const float* W_node       = (const float*)d_in[9];
    const float* attn         = (const float*)d_in[10];
    const float* bias_node    = (const float*)d_in[11];
    float* out = (float*)d_out;

    char* ws = (char*)d_ws;
    size_t off = 0;
    auto alloc = [&](size_t bytes) -> void* {
        void* pp = ws + off;
        off += (bytes + 255) & ~(size_t)255;
        return pp;
    };
    u16*   ef    = (u16*)alloc((size_t)E_EDGES * FE * sizeof(u16));       // 67 MB
    float* p     = (float*)alloc((size_t)E_EDGES * sizeof(float));
    float* z     = (float*)alloc(N_NODES * sizeof(float));
    u16*   fni   = (u16*)alloc(N_NODES * FE * sizeof(u16));
    u16*   fnj   = (u16*)alloc(N_NODES * FE * sizeof(u16));
    float* h     = (float*)alloc(N_NODES * FC * sizeof(float));
    float* S     = (float*)alloc((size_t)N_NODES * N_NODES * sizeof(float)); // 4 MB
    float* nodeA = (float*)alloc(N_NODES * FC * sizeof(float));
    u16*   Wt    = (u16*)alloc((size_t)NLAYERS * FE * FE * sizeof(u16));  // 24 KB

    hipMemcpyAsync(nodeA, node_feature, N_NODES * FC * sizeof(float),
                   hipMemcpyDeviceToDevice, stream);

    wt_kernel<<<(NLAYERS * FE * FE) / 256, 256, 0, stream>>>(W_fij, Wt);
    ef_init_kernel<<<(E_EDGES * 8) / 256, 256, 0, stream>>>(edge_feature, W_in, b_in, ef);

    for (int l = 0; l < NLAYERS; l++) {
        const float* node_in = nodeA;
        float* node_out = (l == NLAYERS - 1) ? out : nodeA;

        node_kernel<<<N_NODES, 256, 0, stream>>>(
            node_in, W_ni + (size_t)l * FC * FE, W_nj + (size_t)l * FC * FE,
            W_node + (size_t)l * FC * FC, bias_node + (size_t)l * FC,
            fni, fnj, h, z);

        hipMemsetAsync(S, 0, (size_t)N_NODES * N_NODES * sizeof(float), stream);

        if (l == NLAYERS - 1) {
            edge_mfma_kernel<false><<<E_EDGES / 64, 256, 0, stream>>>(
                ef, Wt + (size_t)l * FE * FE, fni, fnj, src, dst,
                attn + (size_t)l * FE, p, z);
        } else {
            edge_mfma_kernel<true><<<E_EDGES / 64, 256, 0, stream>>>(
                ef, Wt + (size_t)l * FE * FE, fni, fnj, src, dst,
                attn + (size_t)l * FE, p, z);
        }

        scatter_kernel<<<E_EDGES / 256, 256, 0, stream>>>(p, z, src, dst, S);

        spmm_kernel<<<N_NODES, 256, 0, stream>>>(S, h, node_in, node_out);
    }
}

// Round 6
// 336.021 us; speedup vs baseline: 38.4476x; 2.5493x over previous
//
#include <hip/hip_runtime.h>

#define N_NODES 1024
#define E_EDGES 524288
#define FE 64
#define FC 128
#define NLAYERS 3

typedef unsigned short u16;
typedef __attribute__((ext_vector_type(8))) short bf16x8;   // MFMA A/B frag
typedef __attribute__((ext_vector_type(4))) float f32x4;    // MFMA C/D frag
typedef __attribute__((ext_vector_type(8))) unsigned short u16x8;

__device__ __forceinline__ float bf2f(u16 u) {
    return __uint_as_float(((unsigned)u) << 16);
}
__device__ __forceinline__ u16 f2bf(float f) {
    unsigned x = __float_as_uint(f);
    return (u16)((x + 0x7FFFu + ((x >> 16) & 1u)) >> 16);   // RNE
}

// ---------------------------------------------------------------------------
// Wt[l][n][k] = bf16(W_fij[l][k][n])
// ---------------------------------------------------------------------------
__global__ __launch_bounds__(256) void wt_kernel(
    const float* __restrict__ Wfij, u16* __restrict__ Wt)
{
    const int i = blockIdx.x * 256 + threadIdx.x;   // 3*64*64 total
    const int l = i >> 12, rem = i & 4095;
    const int n = rem >> 6, k = rem & 63;
    Wt[(size_t)l * 4096 + n * 64 + k] = f2bf(Wfij[(size_t)l * 4096 + k * 64 + n]);
}

// ---------------------------------------------------------------------------
// ef[e][f] = bf16(x[e,0]*Win[0,f] + x[e,1]*Win[1,f] + b[f])
// ---------------------------------------------------------------------------
__global__ __launch_bounds__(256) void ef_init_kernel(
    const float* __restrict__ x, const float* __restrict__ Win,
    const float* __restrict__ bin, u16* __restrict__ ef)
{
    const int idx = blockIdx.x * 256 + threadIdx.x;  // E*8 total
    const int e = idx >> 3;
    const int f0 = (idx & 7) * 8;
    const float x0 = x[e * 2], x1 = x[e * 2 + 1];
    u16x8 o;
    #pragma unroll
    for (int j = 0; j < 8; j++) {
        o[j] = f2bf(fmaf(x0, Win[f0 + j], fmaf(x1, Win[FE + f0 + j], bin[f0 + j])));
    }
    *reinterpret_cast<u16x8*>(ef + (size_t)e * FE + f0) = o;
}

// ---------------------------------------------------------------------------
// Node projections: fni/fnj (bf16), h (fp32).
// ---------------------------------------------------------------------------
__global__ __launch_bounds__(256) void node_kernel(
    const float* __restrict__ node,
    const float* __restrict__ Wni, const float* __restrict__ Wnj,
    const float* __restrict__ Wnode, const float* __restrict__ bias,
    u16* __restrict__ fni, u16* __restrict__ fnj,
    float* __restrict__ h)
{
    __shared__ float row[FC];
    const int d = blockIdx.x;
    if (threadIdx.x < FC) row[threadIdx.x] = node[d * FC + threadIdx.x];
    __syncthreads();

    const int t = threadIdx.x;
    if (t < 64) {
        float a = 0.f;
        #pragma unroll 8
        for (int k = 0; k < FC; k++) a = fmaf(row[k], Wni[k * FE + t], a);
        fni[d * FE + t] = f2bf(a);
    } else if (t < 128) {
        const int f = t - 64;
        float a = 0.f;
        #pragma unroll 8
        for (int k = 0; k < FC; k++) a = fmaf(row[k], Wnj[k * FE + f], a);
        fnj[d * FE + f] = f2bf(a);
    } else {
        const int c = t - 128;
        float a = bias[c];
        #pragma unroll 8
        for (int k = 0; k < FC; k++) a = fmaf(row[k], Wnode[k * FC + c], a);
        h[d * FC + c] = a;
    }
}

// ---------------------------------------------------------------------------
// MFMA edge kernel. Wave = 16 edges, block = 4 waves = 64 edges (grid E/64).
// r5 lesson: kernel was latency-bound (all pipes <15%). This version:
//  - stages fni[src]/fnj[dst] rows into LDS with coalesced 16B loads
//    (replaces 32 scalar global gathers per lane),
//  - saves A-fragments (old ef rows) to LDS so the write-back needs no
//    global re-read,
//  - scatters exp(logit) directly into S[dst][src] (z == rowsum(S), taken
//    in spmm) — removes the 512-way-contended z atomics + scatter kernel.
// Fragment layouts (m89 family):
//   A: row=lane&15 (edge), k=(lane>>4)*8+j     B: col=lane&15 (n), same k
//   C: col=lane&15 (n),  row=(lane>>4)*4+reg   (edge)
// ---------------------------------------------------------------------------
template <bool WRITE_EF>
__global__ void edge_mfma_kernel(
    u16* __restrict__ ef,                 // [E][64] bf16 (in/out)
    const u16* __restrict__ Wt,           // [64 n][64 k] bf16 (this layer)
    const u16* __restrict__ fni, const u16* __restrict__ fnj,
    const int* __restrict__ src, const int* __restrict__ dst,
    const float* __restrict__ attn,       // [64] fp32
    float* __restrict__ S)                // [N][N] fp32 (pre-zeroed)
{
    __shared__ __align__(16) u16 stage[4][32][72];               // fni:0-15 fnj:16-31
    __shared__ __align__(16) u16 aef[WRITE_EF ? 4 : 1][16][72];  // old ef rows
    __shared__ __align__(16) u16 fol[WRITE_EF ? 4 : 1][16][72];  // f_out rows

    const int lane = threadIdx.x & 63;
    const int wid  = threadIdx.x >> 6;
    const int l15  = lane & 15;
    const int grp  = lane >> 4;                       // 0..3
    const int wbase = blockIdx.x * 64 + wid * 16;

    // --- coalesced gather of fni[src[e]] / fnj[dst[e]] rows into LDS ---
    #pragma unroll
    for (int it = 0; it < 4; it++) {
        const int ridx = it * 8 + (lane >> 3);        // 0..31
        const int e = wbase + (ridx & 15);
        const int c8 = (lane & 7) * 8;
        const u16* rowp = (ridx < 16) ? (fni + (size_t)src[e] * FE)
                                      : (fnj + (size_t)dst[e] * FE);
        *reinterpret_cast<u16x8*>(&stage[wid][ridx][c8]) =
            *reinterpret_cast<const u16x8*>(rowp + c8);
    }

    // --- A fragments (this wave's 16 ef rows); save for write-back ---
    const size_t arow = (size_t)(wbase + l15) * FE;
    const bf16x8 afr0 = *reinterpret_cast<const bf16x8*>(ef + arow + grp * 8);
    const bf16x8 afr1 = *reinterpret_cast<const bf16x8*>(ef + arow + 32 + grp * 8);
    if constexpr (WRITE_EF) {
        *reinterpret_cast<bf16x8*>(&aef[wid][l15][grp * 8]) = afr0;
        *reinterpret_cast<bf16x8*>(&aef[wid][l15][32 + grp * 8]) = afr1;
    }

    // --- B fragments: Wt[n][k]; n = nt*16+l15, k = ks*32+grp*8+j ---
    bf16x8 bfr[2][4];
    #pragma unroll
    for (int ks = 0; ks < 2; ks++)
        #pragma unroll
        for (int nt = 0; nt < 4; nt++)
            bfr[ks][nt] = *reinterpret_cast<const bf16x8*>(
                Wt + (size_t)(nt * 16 + l15) * 64 + ks * 32 + grp * 8);

    f32x4 acc[4];
    #pragma unroll
    for (int nt = 0; nt < 4; nt++) {
        acc[nt] = (f32x4){0.f, 0.f, 0.f, 0.f};
        acc[nt] = __builtin_amdgcn_mfma_f32_16x16x32_bf16(afr0, bfr[0][nt], acc[nt], 0, 0, 0);
        acc[nt] = __builtin_amdgcn_mfma_f32_16x16x32_bf16(afr1, bfr[1][nt], acc[nt], 0, 0, 0);
    }

    // attn values for this lane's n columns (L1-resident)
    float an[4];
    #pragma unroll
    for (int nt = 0; nt < 4; nt++) an[nt] = attn[nt * 16 + l15];

    __syncthreads();    // stage + aef visible

    // --- epilogue: add gathered rows, leaky_relu, logit partials, f_out→LDS ---
    float logit[4] = {0.f, 0.f, 0.f, 0.f};
    #pragma unroll
    for (int nt = 0; nt < 4; nt++) {
        const int n = nt * 16 + l15;
        #pragma unroll
        for (int r = 0; r < 4; r++) {
            const int row = grp * 4 + r;              // edge slot in wave
            float v = acc[nt][r] + bf2f(stage[wid][row][n])
                                 + bf2f(stage[wid][16 + row][n]);
            v = v > 0.f ? v : 0.2f * v;
            logit[r] = fmaf(v, an[nt], logit[r]);
            if constexpr (WRITE_EF) fol[wid][row][n] = f2bf(v);
        }
    }

    // --- logit reduce (16 lanes/edge) + direct scatter into S ---
    #pragma unroll
    for (int r = 0; r < 4; r++) {
        float t = logit[r];
        t += __shfl_xor(t, 1, 16);
        t += __shfl_xor(t, 2, 16);
        t += __shfl_xor(t, 4, 16);
        t += __shfl_xor(t, 8, 16);
        if (l15 == 0) {
            const int e = wbase + grp * 4 + r;
            atomicAdd(S + (size_t)dst[e] * N_NODES + src[e], expf(t));
        }
    }

    // --- ef write-back: combine old row (LDS) + f_out (LDS), 16B stores ---
    if constexpr (WRITE_EF) {
        __syncthreads();
        #pragma unroll
        for (int q = 0; q < 2; q++) {
            const int row = (lane >> 3) + q * 8;
            const int f0 = (lane & 7) * 8;
            const u16x8 fo = *reinterpret_cast<const u16x8*>(&fol[wid][row][f0]);
            const u16x8 ev = *reinterpret_cast<const u16x8*>(&aef[wid][row][f0]);
            u16x8 o;
            #pragma unroll
            for (int j = 0; j < 8; j++) o[j] = f2bf(bf2f(ev[j]) + bf2f(fo[j]));
            *reinterpret_cast<u16x8*>(ef + (size_t)(wbase + row) * FE + f0) = o;
        }
    }
}

// ---------------------------------------------------------------------------
// node_out = node_in + (S @ h) / rowsum(S).   rowsum(S[d]) == z[d].
// ---------------------------------------------------------------------------
__global__ __launch_bounds__(256) void spmm_kernel(
    const float* __restrict__ S, const float* __restrict__ h,
    const float* __restrict__ nin, float* __restrict__ nout)
{
    __shared__ float red[256];
    __shared__ float rs[2];
    const int d = blockIdx.x;
    const int c = threadIdx.x & 127;
    const int half = threadIdx.x >> 7;
    const float* Srow = S + (size_t)d * N_NODES + half * 512;
    const float* hp = h + (size_t)half * 512 * FC;
    float acc = 0.f, rsum = 0.f;
    #pragma unroll 8
    for (int n = 0; n < 512; n++) {
        const float s = Srow[n];
        rsum += s;
        acc = fmaf(s, hp[n * FC + c], acc);
    }
    red[threadIdx.x] = acc;
    if (c == 0) rs[half] = rsum;
    __syncthreads();
    if (half == 0) {
        nout[d * FC + c] = nin[d * FC + c] + (red[c] + red[128 + c]) / (rs[0] + rs[1]);
    }
}

// ---------------------------------------------------------------------------
extern "C" void kernel_launch(void* const* d_in, const int* in_sizes, int n_in,
                              void* d_out, int out_size, void* d_ws, size_t ws_size,
                              hipStream_t stream)
{
    const float* node_feature = (const float*)d_in[0];
    const float* edge_feature = (const float*)d_in[1];
    const int*   src          = (const int*)d_in[2];
    const int*   dst          = (const int*)d_in[3];
    const float* W_in         = (const float*)d_in[4];
    const float* b_in         = (const float*)d_in[5];
    const float* W_ni         = (const float*)d_in[6];
    const float* W_nj         = (const float*)d_in[7];
    const float* W_fij        = (const float*)d_in[8];
    const float* W_node       = (const float*)d_in[9];
    const float* attn         = (const float*)d_in[10];
    const float* bias_node    = (const float*)d_in[11];
    float* out = (float*)d_out;

    char* ws = (char*)d_ws;
    size_t off = 0;
    auto alloc = [&](size_t bytes) -> void* {
        void* pp = ws + off;
        off += (bytes + 255) & ~(size_t)255;
        return pp;
    };
    u16*   ef    = (u16*)alloc((size_t)E_EDGES * FE * sizeof(u16));       // 67 MB
    u16*   fni   = (u16*)alloc(N_NODES * FE * sizeof(u16));
    u16*   fnj   = (u16*)alloc(N_NODES * FE * sizeof(u16));
    float* h     = (float*)alloc(N_NODES * FC * sizeof(float));
    float* S     = (float*)alloc((size_t)N_NODES * N_NODES * sizeof(float)); // 4 MB
    float* nodeA = (float*)alloc(N_NODES * FC * sizeof(float));
    u16*   Wt    = (u16*)alloc((size_t)NLAYERS * FE * FE * sizeof(u16));  // 24 KB

    hipMemcpyAsync(nodeA, node_feature, N_NODES * FC * sizeof(float),
                   hipMemcpyDeviceToDevice, stream);

    wt_kernel<<<(NLAYERS * FE * FE) / 256, 256, 0, stream>>>(W_fij, Wt);
    ef_init_kernel<<<(E_EDGES * 8) / 256, 256, 0, stream>>>(edge_feature, W_in, b_in, ef);

    for (int l = 0; l < NLAYERS; l++) {
        const float* node_in = nodeA;
        float* node_out = (l == NLAYERS - 1) ? out : nodeA;

        node_kernel<<<N_NODES, 256, 0, stream>>>(
            node_in, W_ni + (size_t)l * FC * FE, W_nj + (size_t)l * FC * FE,
            W_node + (size_t)l * FC * FC, bias_node + (size_t)l * FC,
            fni, fnj, h);

        hipMemsetAsync(S, 0, (size_t)N_NODES * N_NODES * sizeof(float), stream);

        if (l == NLAYERS - 1) {
            edge_mfma_kernel<false><<<E_EDGES / 64, 256, 0, stream>>>(
                ef, Wt + (size_t)l * FE * FE, fni, fnj, src, dst,
                attn + (size_t)l * FE, S);
        } else {
            edge_mfma_kernel<true><<<E_EDGES / 64, 256, 0, stream>>>(
                ef, Wt + (size_t)l * FE * FE, fni, fnj, src, dst,
                attn + (size_t)l * FE, S);
        }

        spmm_kernel<<<N_NODES, 256, 0, stream>>>(S, h, node_in, node_out);
    }
}

// Round 7
// 285.421 us; speedup vs baseline: 45.2638x; 1.1773x over previous
//
#include <hip/hip_runtime.h>

#define N_NODES 1024
#define E_EDGES 524288
#define FE 64
#define FC 128
#define NLAYERS 3

typedef unsigned short u16;
typedef __attribute__((ext_vector_type(8))) short bf16x8;   // MFMA A/B frag
typedef __attribute__((ext_vector_type(4))) float f32x4;    // MFMA C/D frag
typedef __attribute__((ext_vector_type(8))) unsigned short u16x8;

__device__ __forceinline__ float bf2f(u16 u) {
    return __uint_as_float(((unsigned)u) << 16);
}
__device__ __forceinline__ u16 f2bf(float f) {
    unsigned x = __float_as_uint(f);
    return (u16)((x + 0x7FFFu + ((x >> 16) & 1u)) >> 16);   // RNE
}

// ---------------------------------------------------------------------------
// Setup (1024 blocks, one per node): zero S row, copy node->nodeA, transpose
// W_fij into bf16 Wt (blocks 0..47), and layer-0 projections fni/fnj/h.
// ---------------------------------------------------------------------------
__global__ __launch_bounds__(256) void setup_kernel(
    const float* __restrict__ node_feature, const float* __restrict__ Wfij,
    u16* __restrict__ Wt,
    const float* __restrict__ Wni, const float* __restrict__ Wnj,
    const float* __restrict__ Wnode, const float* __restrict__ bias,
    u16* __restrict__ fni, u16* __restrict__ fnj,
    float* __restrict__ h, float* __restrict__ S, float* __restrict__ nodeA)
{
    __shared__ float row[FC];
    const int d = blockIdx.x;
    const int t = threadIdx.x;

    reinterpret_cast<float4*>(S + (size_t)d * N_NODES)[t] = make_float4(0.f, 0.f, 0.f, 0.f);

    if (t < FC) {
        const float v = node_feature[d * FC + t];
        nodeA[d * FC + t] = v;
        row[t] = v;
    }
    if (d < (NLAYERS * FE * FE) / 256) {
        const int i = d * 256 + t;
        const int l = i >> 12, rem = i & 4095;
        const int n = rem >> 6, k = rem & 63;
        Wt[(size_t)l * 4096 + n * 64 + k] = f2bf(Wfij[(size_t)l * 4096 + k * 64 + n]);
    }
    __syncthreads();

    if (t < 64) {
        float a = 0.f;
        #pragma unroll 8
        for (int k = 0; k < FC; k++) a = fmaf(row[k], Wni[k * FE + t], a);
        fni[d * FE + t] = f2bf(a);
    } else if (t < 128) {
        const int f = t - 64;
        float a = 0.f;
        #pragma unroll 8
        for (int k = 0; k < FC; k++) a = fmaf(row[k], Wnj[k * FE + f], a);
        fnj[d * FE + f] = f2bf(a);
    } else {
        const int c = t - 128;
        float a = bias[c];
        #pragma unroll 8
        for (int k = 0; k < FC; k++) a = fmaf(row[k], Wnode[k * FC + c], a);
        h[d * FC + c] = a;
    }
}

// ---------------------------------------------------------------------------
// MFMA edge kernel. Wave = 16 edges, block = 4 waves (grid E/64), no loop,
// no block barriers (stage/fol are wave-local; same-wave DS ops are ordered;
// wave_barrier pins compiler ordering at LDS handoffs).
// FIRST: A-fragments computed from edge_feature@W_in+b_in in registers
//        (ef_init fused away). Else loaded from ef.
// WRITE_EF: ef' = ef + f_out written back from A-frag REGISTERS + fol LDS
//        transpose (r6's aef LDS buffer removed).
// Scatters exp(logit) straight into S[dst][src]; z == rowsum(S) in spmm.
// Fragment layouts (m89 family):
//   A: row=lane&15 (edge), k=(lane>>4)*8+j     B: col=lane&15 (n), same k
//   C: col=lane&15 (n),  row=(lane>>4)*4+reg   (edge)
// ---------------------------------------------------------------------------
template <bool FIRST, bool WRITE_EF>
__global__ void edge_mfma_kernel(
    u16* __restrict__ ef,                 // [E][64] bf16 (in/out)
    const float* __restrict__ x,          // [E][2]   (FIRST only)
    const float* __restrict__ Win,        // [2][64]  (FIRST only)
    const float* __restrict__ bin,        // [64]     (FIRST only)
    const u16* __restrict__ Wt,           // [64 n][64 k] bf16 (this layer)
    const u16* __restrict__ fni, const u16* __restrict__ fnj,
    const int* __restrict__ src, const int* __restrict__ dst,
    const float* __restrict__ attn,       // [64] fp32
    float* __restrict__ S)                // [N][N] fp32 (pre-zeroed)
{
    __shared__ __align__(16) u16 stage[4][32][72];               // fni:0-15 fnj:16-31
    __shared__ __align__(16) u16 fol[WRITE_EF ? 4 : 1][16][72];  // f_out rows

    const int lane = threadIdx.x & 63;
    const int wid  = threadIdx.x >> 6;
    const int l15  = lane & 15;
    const int grp  = lane >> 4;                       // 0..3
    const int wbase = blockIdx.x * 64 + wid * 16;

    // --- coalesced gather of fni[src[e]] / fnj[dst[e]] rows into LDS ---
    #pragma unroll
    for (int it = 0; it < 4; it++) {
        const int ridx = it * 8 + (lane >> 3);        // 0..31
        const int e = wbase + (ridx & 15);
        const int c8 = (lane & 7) * 8;
        const u16* rowp = (ridx < 16) ? (fni + (size_t)src[e] * FE)
                                      : (fnj + (size_t)dst[e] * FE);
        *reinterpret_cast<u16x8*>(&stage[wid][ridx][c8]) =
            *reinterpret_cast<const u16x8*>(rowp + c8);
    }

    // --- A fragments: row = wbase+l15, k = half*32 + grp*8 + j ---
    bf16x8 afr0, afr1;
    if constexpr (FIRST) {
        const float2 xx = *reinterpret_cast<const float2*>(x + 2 * (size_t)(wbase + l15));
        #pragma unroll
        for (int half = 0; half < 2; half++) {
            const int c0 = half * 32 + grp * 8;
            const float4 wA0 = *reinterpret_cast<const float4*>(Win + c0);
            const float4 wA1 = *reinterpret_cast<const float4*>(Win + c0 + 4);
            const float4 wB0 = *reinterpret_cast<const float4*>(Win + FE + c0);
            const float4 wB1 = *reinterpret_cast<const float4*>(Win + FE + c0 + 4);
            const float4 b0  = *reinterpret_cast<const float4*>(bin + c0);
            const float4 b1  = *reinterpret_cast<const float4*>(bin + c0 + 4);
            bf16x8 fr;
            fr[0] = (short)f2bf(fmaf(xx.x, wA0.x, fmaf(xx.y, wB0.x, b0.x)));
            fr[1] = (short)f2bf(fmaf(xx.x, wA0.y, fmaf(xx.y, wB0.y, b0.y)));
            fr[2] = (short)f2bf(fmaf(xx.x, wA0.z, fmaf(xx.y, wB0.z, b0.z)));
            fr[3] = (short)f2bf(fmaf(xx.x, wA0.w, fmaf(xx.y, wB0.w, b0.w)));
            fr[4] = (short)f2bf(fmaf(xx.x, wA1.x, fmaf(xx.y, wB1.x, b1.x)));
            fr[5] = (short)f2bf(fmaf(xx.x, wA1.y, fmaf(xx.y, wB1.y, b1.y)));
            fr[6] = (short)f2bf(fmaf(xx.x, wA1.z, fmaf(xx.y, wB1.z, b1.z)));
            fr[7] = (short)f2bf(fmaf(xx.x, wA1.w, fmaf(xx.y, wB1.w, b1.w)));
            if (half == 0) afr0 = fr; else afr1 = fr;
        }
    } else {
        const size_t arow = (size_t)(wbase + l15) * FE;
        afr0 = *reinterpret_cast<const bf16x8*>(ef + arow + grp * 8);
        afr1 = *reinterpret_cast<const bf16x8*>(ef + arow + 32 + grp * 8);
    }

    // --- B fragments: Wt[n][k]; n = nt*16+l15, k = ks*32+grp*8+j ---
    bf16x8 bfr[2][4];
    #pragma unroll
    for (int ks = 0; ks < 2; ks++)
        #pragma unroll
        for (int nt = 0; nt < 4; nt++)
            bfr[ks][nt] = *reinterpret_cast<const bf16x8*>(
                Wt + (size_t)(nt * 16 + l15) * 64 + ks * 32 + grp * 8);

    f32x4 acc[4];
    #pragma unroll
    for (int nt = 0; nt < 4; nt++) {
        acc[nt] = (f32x4){0.f, 0.f, 0.f, 0.f};
        acc[nt] = __builtin_amdgcn_mfma_f32_16x16x32_bf16(afr0, bfr[0][nt], acc[nt], 0, 0, 0);
        acc[nt] = __builtin_amdgcn_mfma_f32_16x16x32_bf16(afr1, bfr[1][nt], acc[nt], 0, 0, 0);
    }

    float an[4];
    #pragma unroll
    for (int nt = 0; nt < 4; nt++) an[nt] = attn[nt * 16 + l15];

    __builtin_amdgcn_wave_barrier();   // stage writes <-> epilogue reads

    // --- epilogue: add gathered rows, leaky_relu, logit partials, f_out→LDS ---
    float logit[4] = {0.f, 0.f, 0.f, 0.f};
    #pragma unroll
    for (int nt = 0; nt < 4; nt++) {
        const int n = nt * 16 + l15;
        #pragma unroll
        for (int r = 0; r < 4; r++) {
            const int row = grp * 4 + r;              // edge slot in wave
            float v = acc[nt][r] + bf2f(stage[wid][row][n])
                                 + bf2f(stage[wid][16 + row][n]);
            v = v > 0.f ? v : 0.2f * v;
            logit[r] = fmaf(v, an[nt], logit[r]);
            if constexpr (WRITE_EF) fol[wid][row][n] = f2bf(v);
        }
    }

    // --- logit reduce (16 lanes/edge) + direct scatter into S ---
    #pragma unroll
    for (int r = 0; r < 4; r++) {
        float t = logit[r];
        t += __shfl_xor(t, 1, 16);
        t += __shfl_xor(t, 2, 16);
        t += __shfl_xor(t, 4, 16);
        t += __shfl_xor(t, 8, 16);
        if (l15 == 0) {
            const int e = wbase + grp * 4 + r;
            atomicAdd(S + (size_t)dst[e] * N_NODES + src[e], expf(t));
        }
    }

    // --- ef write-back from A-frag registers + fol LDS (A layout: row=l15,
    //     cols grp*8.. and 32+grp*8..), 16B stores ---
    if constexpr (WRITE_EF) {
        __builtin_amdgcn_wave_barrier();   // fol writes <-> fol reads
        const u16x8 fo0 = *reinterpret_cast<const u16x8*>(&fol[wid][l15][grp * 8]);
        const u16x8 fo1 = *reinterpret_cast<const u16x8*>(&fol[wid][l15][32 + grp * 8]);
        u16x8 o0, o1;
        #pragma unroll
        for (int j = 0; j < 8; j++) {
            o0[j] = f2bf(bf2f((u16)afr0[j]) + bf2f(fo0[j]));
            o1[j] = f2bf(bf2f((u16)afr1[j]) + bf2f(fo1[j]));
        }
        u16* gp = ef + (size_t)(wbase + l15) * FE;
        *reinterpret_cast<u16x8*>(gp + grp * 8) = o0;
        *reinterpret_cast<u16x8*>(gp + 32 + grp * 8) = o1;
    }
}

// ---------------------------------------------------------------------------
// spmm (+fusions): nout = nin + (S@h)/rowsum(S).  For !LAST additionally:
// re-zero S row (for next layer), write nodeA, and compute next-layer
// projections fni/fnj/h_next from the fresh node row (h double-buffered:
// blocks read h globally, so next-layer h must go to the other buffer).
// ---------------------------------------------------------------------------
template <bool LAST>
__global__ __launch_bounds__(256) void spmm_kernel(
    float* __restrict__ S, const float* __restrict__ h,
    const float* __restrict__ nin, float* __restrict__ nout,
    const float* __restrict__ Wni, const float* __restrict__ Wnj,
    const float* __restrict__ Wnode, const float* __restrict__ bias,
    u16* __restrict__ fni, u16* __restrict__ fnj, float* __restrict__ hnext)
{
    __shared__ float red[256];
    __shared__ float rs[2];
    __shared__ float row[FC];
    const int d = blockIdx.x;
    const int t = threadIdx.x;
    const int c = t & 127;
    const int half = t >> 7;
    const float* Srow = S + (size_t)d * N_NODES + half * 512;
    const float* hp = h + (size_t)half * 512 * FC;
    float acc = 0.f, rsum = 0.f;
    #pragma unroll 8
    for (int n = 0; n < 512; n++) {
        const float s = Srow[n];
        rsum += s;
        acc = fmaf(s, hp[n * FC + c], acc);
    }
    red[t] = acc;
    if (c == 0) rs[half] = rsum;
    __syncthreads();

    if constexpr (!LAST) {   // re-zero S row for next layer (reads done)
        reinterpret_cast<float4*>(S + (size_t)d * N_NODES)[t] = make_float4(0.f, 0.f, 0.f, 0.f);
    }
    if (half == 0) {
        const float v = nin[d * FC + c] + (red[c] + red[128 + c]) / (rs[0] + rs[1]);
        nout[d * FC + c] = v;
        if constexpr (!LAST) row[c] = v;
    }

    if constexpr (!LAST) {
        __syncthreads();
        if (t < 64) {
            float a = 0.f;
            #pragma unroll 8
            for (int k = 0; k < FC; k++) a = fmaf(row[k], Wni[k * FE + t], a);
            fni[d * FE + t] = f2bf(a);
        } else if (t < 128) {
            const int f = t - 64;
            float a = 0.f;
            #pragma unroll 8
            for (int k = 0; k < FC; k++) a = fmaf(row[k], Wnj[k * FE + f], a);
            fnj[d * FE + f] = f2bf(a);
        } else {
            const int cc = t - 128;
            float a = bias[cc];
            #pragma unroll 8
            for (int k = 0; k < FC; k++) a = fmaf(row[k], Wnode[k * FC + cc], a);
            hnext[d * FC + cc] = a;
        }
    }
}

// ---------------------------------------------------------------------------
extern "C" void kernel_launch(void* const* d_in, const int* in_sizes, int n_in,
                              void* d_out, int out_size, void* d_ws, size_t ws_size,
                              hipStream_t stream)
{
    const float* node_feature = (const float*)d_in[0];
    const float* edge_feature = (const float*)d_in[1];
    const int*   src          = (const int*)d_in[2];
    const int*   dst          = (const int*)d_in[3];
    const float* W_in         = (const float*)d_in[4];
    const float* b_in         = (const float*)d_in[5];
    const float* W_ni         = (const float*)d_in[6];
    const float* W_nj         = (const float*)d_in[7];
    const float* W_fij        = (const float*)d_in[8];
    const float* W_node       = (const float*)d_in[9];
    const float* attn         = (const float*)d_in[10];
    const float* bias_node    = (const float*)d_in[11];
    float* out = (float*)d_out;

    char* ws = (char*)d_ws;
    size_t off = 0;
    auto alloc = [&](size_t bytes) -> void* {
        void* pp = ws + off;
        off += (bytes + 255) & ~(size_t)255;
        return pp;
    };
    u16*   ef    = (u16*)alloc((size_t)E_EDGES * FE * sizeof(u16));       // 67 MB
    u16*   fni   = (u16*)alloc(N_NODES * FE * sizeof(u16));
    u16*   fnj   = (u16*)alloc(N_NODES * FE * sizeof(u16));
    float* h0    = (float*)alloc(N_NODES * FC * sizeof(float));
    float* h1    = (float*)alloc(N_NODES * FC * sizeof(float));
    float* S     = (float*)alloc((size_t)N_NODES * N_NODES * sizeof(float)); // 4 MB
    float* nodeA = (float*)alloc(N_NODES * FC * sizeof(float));
    u16*   Wt    = (u16*)alloc((size_t)NLAYERS * FE * FE * sizeof(u16));  // 24 KB
    float* hbuf[2] = {h0, h1};

    setup_kernel<<<N_NODES, 256, 0, stream>>>(
        node_feature, W_fij, Wt, W_ni, W_nj, W_node, bias_node,
        fni, fnj, h0, S, nodeA);

    for (int l = 0; l < NLAYERS; l++) {
        float* hl = hbuf[l & 1];
        float* hn = hbuf[(l + 1) & 1];

        if (l == 0) {
            edge_mfma_kernel<true, true><<<E_EDGES / 64, 256, 0, stream>>>(
                ef, edge_feature, W_in, b_in, Wt + (size_t)l * FE * FE,
                fni, fnj, src, dst, attn + (size_t)l * FE, S);
        } else if (l == NLAYERS - 1) {
            edge_mfma_kernel<false, false><<<E_EDGES / 64, 256, 0, stream>>>(
                ef, nullptr, nullptr, nullptr, Wt + (size_t)l * FE * FE,
                fni, fnj, src, dst, attn + (size_t)l * FE, S);
        } else {
            edge_mfma_kernel<false, true><<<E_EDGES / 64, 256, 0, stream>>>(
                ef, nullptr, nullptr, nullptr, Wt + (size_t)l * FE * FE,
                fni, fnj, src, dst, attn + (size_t)l * FE, S);
        }

        if (l == NLAYERS - 1) {
            spmm_kernel<true><<<N_NODES, 256, 0, stream>>>(
                S, hl, nodeA, out,
                nullptr, nullptr, nullptr, nullptr, nullptr, nullptr, nullptr);
        } else {
            const int ln = l + 1;
            spmm_kernel<false><<<N_NODES, 256, 0, stream>>>(
                S, hl, nodeA, nodeA,
                W_ni + (size_t)ln * FC * FE, W_nj + (size_t)ln * FC * FE,
                W_node + (size_t)ln * FC * FC, bias_node + (size_t)ln * FC,
                fni, fnj, hn);
        }
    }
}